// Round 14
// baseline (152.624 us; speedup 1.0000x reference)
//
#include <hip/hip_runtime.h>
#include <hip/hip_bf16.h>

#define N_V   100000
#define N_E   100000
#define NNZ_C 800000
#define HC    128
#define H_    8
#define C_    16
#define NEG   0.2f
#define BSH   9                      // bucket shift: 512 keys per bucket
#define KPB   512
#define NBUCK 196                    // ceil(100000/512)
#define CAP   5120                   // staging capacity per bucket (mean ~4082, >15 sigma)
#define CHUNK 4096                   // elements per bscatter block (196 blocks)
#define SCAT_NB ((NNZ_C + CHUNK - 1) / CHUNK)
#define GEMM_NB ((N_V + 63) / 64)    // 1563: 64 rows per block, 16 per wave

typedef __attribute__((ext_vector_type(8))) short bf16x8;
typedef __attribute__((ext_vector_type(4))) float f32x4;

__device__ __forceinline__ short f2bf(float f) {
    unsigned u = __float_as_uint(f);
    unsigned r = (u + 0x7FFFu + ((u >> 16) & 1u)) >> 16;   // RNE
    return (short)r;
}
__device__ __forceinline__ float bf2f(unsigned short u) {
    return __uint_as_float(((unsigned)u) << 16);
}
__device__ __forceinline__ unsigned pack2(float lo, float hi) {
    return ((unsigned)(unsigned short)f2bf(hi) << 16) | (unsigned short)f2bf(lo);
}
__device__ __forceinline__ void acc8w(float* acc, uint4 p, float wt) {
    acc[0] += __uint_as_float(p.x << 16) * wt;
    acc[1] += __uint_as_float(p.x & 0xFFFF0000u) * wt;
    acc[2] += __uint_as_float(p.y << 16) * wt;
    acc[3] += __uint_as_float(p.y & 0xFFFF0000u) * wt;
    acc[4] += __uint_as_float(p.z << 16) * wt;
    acc[5] += __uint_as_float(p.z & 0xFFFF0000u) * wt;
    acc[6] += __uint_as_float(p.w << 16) * wt;
    acc[7] += __uint_as_float(p.w & 0xFFFF0000u) * wt;
}
__device__ __forceinline__ void acc8(float* acc, uint4 p) {
    acc[0] += __uint_as_float(p.x << 16);
    acc[1] += __uint_as_float(p.x & 0xFFFF0000u);
    acc[2] += __uint_as_float(p.y << 16);
    acc[3] += __uint_as_float(p.y & 0xFFFF0000u);
    acc[4] += __uint_as_float(p.z << 16);
    acc[5] += __uint_as_float(p.z & 0xFFFF0000u);
    acc[6] += __uint_as_float(p.w << 16);
    acc[7] += __uint_as_float(p.w & 0xFFFF0000u);
}

// ---------------- W -> MFMA B-fragment order (see R13) ----------------
__global__ __launch_bounds__(256) void wt_k(const float* __restrict__ W, unsigned short* __restrict__ Wf) {
    int i = blockIdx.x * 256 + threadIdx.x;    // 16384 elements
    int j    = i & 7;
    int lane = (i >> 3) & 63;
    int ct   = (i >> 9) & 7;
    int ks   = i >> 12;
    int kq = lane >> 4, cl = lane & 15;
    int k = 32 * ks + ((j < 4) ? (4 * kq + j) : (16 + 4 * kq + (j - 4)));
    int c = 16 * ct + cl;
    Wf[i] = (unsigned short)f2bf(W[k * 128 + c]);
}

// ---------------- fused A: bscatter (blocks 0..SCAT_NB-1)  ||  no-LDS MFMA GEMM ----------------
__global__ __launch_bounds__(256) void fusedA_k(const float* __restrict__ X,
                                                const unsigned short* __restrict__ Wf,
                                                unsigned short* __restrict__ X0b,
                                                const int* __restrict__ edges,
                                                const int* __restrict__ vertex,
                                                int* __restrict__ bcur_e, int* __restrict__ bcur_v,
                                                unsigned* __restrict__ stage_e, unsigned* __restrict__ stage_v) {
    __shared__ int he[NBUCK], hv[NBUCK];       // scatter half only (1.6 KB)
    int tid = threadIdx.x;

    if (blockIdx.x >= SCAT_NB) {
        int blk = blockIdx.x - SCAT_NB;
        int lane = tid & 63;
        int cl = lane & 15, kq = lane >> 4;
        int base = blk * 64 + (tid >> 6) * 16;
        int rowA = base + cl;
        int srcRow = (rowA < N_V) ? rowA : (N_V - 1);

        f32x4 acc[8] = {};
        const float4* X4 = (const float4*)X;
        const bf16x8* Wf8 = (const bf16x8*)Wf;

        #pragma unroll
        for (int ks = 0; ks < 4; ++ks) {
            float4 a0 = X4[(size_t)srcRow * 32 + 8 * ks + kq];
            float4 a1 = X4[(size_t)srcRow * 32 + 8 * ks + 4 + kq];
            bf16x8 af;
            af[0] = f2bf(a0.x); af[1] = f2bf(a0.y); af[2] = f2bf(a0.z); af[3] = f2bf(a0.w);
            af[4] = f2bf(a1.x); af[5] = f2bf(a1.y); af[6] = f2bf(a1.z); af[7] = f2bf(a1.w);
            #pragma unroll
            for (int ct = 0; ct < 8; ++ct) {
                bf16x8 bf = Wf8[((ks * 8 + ct) << 6) + lane];   // coalesced, L1-hot
                acc[ct] = __builtin_amdgcn_mfma_f32_16x16x32_bf16(af, bf, acc[ct], 0, 0, 0);
            }
        }
        int rbase = base + kq * 4;
        #pragma unroll
        for (int ct = 0; ct < 8; ++ct) {
            #pragma unroll
            for (int r = 0; r < 4; ++r) {
                int row = rbase + r;
                if (row < N_V) X0b[(size_t)row * 128 + ct * 16 + cl] = (unsigned short)f2bf(acc[ct][r]);
            }
        }
    } else {
        for (int i = tid; i < NBUCK; i += 256) { he[i] = 0; hv[i] = 0; }
        __syncthreads();
        int e0 = blockIdx.x * CHUNK;
        int e1 = e0 + CHUNK; if (e1 > NNZ_C) e1 = NNZ_C;
        for (int i = e0 + tid; i < e1; i += 256) {
            atomicAdd(&he[edges[i] >> BSH], 1);
            atomicAdd(&hv[vertex[i] >> BSH], 1);
        }
        __syncthreads();
        for (int i = tid; i < NBUCK; i += 256) {
            int c = he[i]; he[i] = c ? atomicAdd(&bcur_e[i], c) : 0;
            c = hv[i];     hv[i] = c ? atomicAdd(&bcur_v[i], c) : 0;
        }
        __syncthreads();
        for (int i = e0 + tid; i < e1; i += 256) {
            int ed = edges[i], v = vertex[i];
            int be = ed >> BSH, bv = v >> BSH;
            int pe = atomicAdd(&he[be], 1);
            stage_e[(size_t)be * CAP + pe] = ((unsigned)(ed & (KPB - 1)) << 17) | (unsigned)v;
            int pv = atomicAdd(&hv[bv], 1);
            stage_v[(size_t)bv * CAP + pv] = ((unsigned)(v & (KPB - 1)) << 17) | (unsigned)ed;
        }
    }
}

// ---------------- bsort: per-bucket counting sort; self-computes global bases ----------------
__global__ __launch_bounds__(512) void bsort_k(const unsigned* __restrict__ stage_e,
                                               const unsigned* __restrict__ stage_v,
                                               const int* __restrict__ bcur_e, const int* __restrict__ bcur_v,
                                               int* __restrict__ e_off, int* __restrict__ v_off,
                                               int* __restrict__ e_idx, int* __restrict__ v_idx) {
    bool isE = blockIdx.x < NBUCK;
    int b = isE ? blockIdx.x : blockIdx.x - NBUCK;
    const unsigned* stage = (isE ? stage_e : stage_v) + (size_t)b * CAP;
    const int* bcnt = isE ? bcur_e : bcur_v;
    int* off = isE ? e_off : v_off;
    int* idx = isE ? e_idx : v_idx;
    int t = threadIdx.x;

    __shared__ int sb[256];
    __shared__ int cntk[KPB];
    __shared__ int loc[KPB];
    if (t < 256) sb[t] = (t < NBUCK) ? bcnt[t] : 0;
    cntk[t] = 0;
    __syncthreads();
    for (int dd = 1; dd < 256; dd <<= 1) {
        int v = (t < 256 && t >= dd) ? sb[t - dd] : 0;
        __syncthreads();
        if (t < 256 && t >= dd) sb[t] += v;
        __syncthreads();
    }
    int cnt = bcnt[b];
    int bbase = sb[b] - cnt;

    for (int i = t; i < cnt; i += 512)
        atomicAdd(&cntk[stage[i] >> 17], 1);
    __syncthreads();
    int val = cntk[t];
    loc[t] = val;
    __syncthreads();
    for (int dd = 1; dd < 512; dd <<= 1) {
        int tv = (t >= dd) ? loc[t - dd] : 0;
        __syncthreads();
        loc[t] += tv;
        __syncthreads();
    }
    int pos0 = bbase + loc[t] - val;
    int key = (b << BSH) + t;
    if (key < N_V) off[key] = pos0;
    cntk[t] = pos0;
    __syncthreads();
    for (int i = t; i < cnt; i += 512) {
        unsigned p = stage[i];
        int pos = atomicAdd(&cntk[p >> 17], 1);
        idx[pos] = (int)(p & 0x1FFFF);
    }
    if (blockIdx.x == 0 && t == 0) { e_off[N_E] = NNZ_C; v_off[N_V] = NNZ_C; }
}

// ---------------- edge aggregation: 16 lanes per EDGE (4 edges/wave), no cross-group reduce ----
// lane j owns channels 8j..8j+7 for all incidences; writes pre-exp'd leaky logits.
__global__ __launch_bounds__(256) void agg_gather_k(const uint4* __restrict__ X0b4,
                                                    const int* __restrict__ e_off,
                                                    const int* __restrict__ e_idx,
                                                    const float* __restrict__ att,
                                                    uint4* __restrict__ Xeb4,
                                                    float* __restrict__ aexp) {
    int lane = threadIdx.x & 63;
    int s = lane >> 4, j = lane & 15;
    int e = ((int)(blockIdx.x * 256 + threadIdx.x) >> 6) * 4 + s;   // N_E % 4 == 0
    int beg = e_off[e], end = e_off[e + 1];
    int deg = end - beg;
    int sbase = s << 4;

    float acc[8] = {0.f, 0.f, 0.f, 0.f, 0.f, 0.f, 0.f, 0.f};
    const uint4 Z = {0u, 0u, 0u, 0u};

    for (int i0 = 0; i0 < deg; i0 += 16) {
        int rem = deg - i0;
        int myidx = (j < rem) ? e_idx[beg + i0 + j] : 0;
        int lim = (rem < 16) ? rem : 16;
        for (int t = 0; t < lim; t += 4) {
            int v_0 = __shfl(myidx, sbase + t);
            int v_1 = __shfl(myidx, sbase + ((t + 1) & 15));
            int v_2 = __shfl(myidx, sbase + ((t + 2) & 15));
            int v_3 = __shfl(myidx, sbase + ((t + 3) & 15));
            bool c1 = (t + 1) < lim, c2 = (t + 2) < lim, c3 = (t + 3) < lim;
            uint4 p_0 = X0b4[(size_t)v_0 * 16 + j];
            uint4 p_1 = c1 ? X0b4[(size_t)v_1 * 16 + j] : Z;
            uint4 p_2 = c2 ? X0b4[(size_t)v_2 * 16 + j] : Z;
            uint4 p_3 = c3 ? X0b4[(size_t)v_3 * 16 + j] : Z;
            acc8(acc, p_0); acc8(acc, p_1); acc8(acc, p_2); acc8(acc, p_3);
        }
    }
    float inv = 1.f / fmaxf((float)deg, 1.f);
    uint4 o;
    o.x = pack2(acc[0] * inv, acc[1] * inv);
    o.y = pack2(acc[2] * inv, acc[3] * inv);
    o.z = pack2(acc[4] * inv, acc[5] * inv);
    o.w = pack2(acc[6] * inv, acc[7] * inv);
    Xeb4[(size_t)e * 16 + j] = o;

    // logit partial over this lane's 8 channels (from ROUNDED values), pair-reduce to head
    const float4* att4 = (const float4*)att;
    float4 A0 = att4[2 * j], A1 = att4[2 * j + 1];
    float s2 = bf2f((unsigned short)(o.x & 0xFFFF)) * A0.x + bf2f((unsigned short)(o.x >> 16)) * A0.y
             + bf2f((unsigned short)(o.y & 0xFFFF)) * A0.z + bf2f((unsigned short)(o.y >> 16)) * A0.w
             + bf2f((unsigned short)(o.z & 0xFFFF)) * A1.x + bf2f((unsigned short)(o.z >> 16)) * A1.y
             + bf2f((unsigned short)(o.w & 0xFFFF)) * A1.z + bf2f((unsigned short)(o.w >> 16)) * A1.w;
    s2 += __shfl_xor(s2, 1);
    if ((j & 1) == 0) {
        s2 = (s2 >= 0.f) ? s2 : NEG * s2;               // leaky
        aexp[e * 8 + (j >> 1)] = __expf(s2);            // PRE-EXP'D weight
    }
}

// ---------------- fused softmax + weighted gather: 16 lanes per VERTEX, single-pass no-max ----
// lane j owns channels 8j..8j+7 and head h=j>>1's denominator — zero cross-lane epilogue.
__global__ __launch_bounds__(256) void out_fused_k(const uint4* __restrict__ Xeb4,
                                                   const float* __restrict__ aexp,
                                                   const int* __restrict__ v_off,
                                                   const int* __restrict__ v_idx,
                                                   float* __restrict__ out) {
    int lane = threadIdx.x & 63;
    int s = lane >> 4, j = lane & 15, h = j >> 1;
    int v = ((int)(blockIdx.x * 256 + threadIdx.x) >> 6) * 4 + s;   // N_V % 4 == 0
    int beg = v_off[v], end = v_off[v + 1];
    int deg = end - beg;
    int sbase = s << 4;

    float acc[8] = {0.f, 0.f, 0.f, 0.f, 0.f, 0.f, 0.f, 0.f};
    float d = 0.f;
    const uint4 Z = {0u, 0u, 0u, 0u};

    for (int i0 = 0; i0 < deg; i0 += 16) {
        int rem = deg - i0;
        int myidx = (j < rem) ? v_idx[beg + i0 + j] : 0;
        int lim = (rem < 16) ? rem : 16;
        for (int t = 0; t < lim; t += 4) {
            int e_0 = __shfl(myidx, sbase + t);
            int e_1 = __shfl(myidx, sbase + ((t + 1) & 15));
            int e_2 = __shfl(myidx, sbase + ((t + 2) & 15));
            int e_3 = __shfl(myidx, sbase + ((t + 3) & 15));
            bool c1 = (t + 1) < lim, c2 = (t + 2) < lim, c3 = (t + 3) < lim;
            float w_0 = aexp[e_0 * 8 + h];
            float w_1 = c1 ? aexp[e_1 * 8 + h] : 0.f;
            float w_2 = c2 ? aexp[e_2 * 8 + h] : 0.f;
            float w_3 = c3 ? aexp[e_3 * 8 + h] : 0.f;
            uint4 p_0 = Xeb4[(size_t)e_0 * 16 + j];
            uint4 p_1 = c1 ? Xeb4[(size_t)e_1 * 16 + j] : Z;
            uint4 p_2 = c2 ? Xeb4[(size_t)e_2 * 16 + j] : Z;
            uint4 p_3 = c3 ? Xeb4[(size_t)e_3 * 16 + j] : Z;
            d += w_0 + w_1 + w_2 + w_3;
            acc8w(acc, p_0, w_0); acc8w(acc, p_1, w_1);
            acc8w(acc, p_2, w_2); acc8w(acc, p_3, w_3);
        }
    }
    float rd = 1.f / (d + 1e-16f);
    float4* out4 = (float4*)out;
    float4 o0 = {acc[0] * rd, acc[1] * rd, acc[2] * rd, acc[3] * rd};
    float4 o1 = {acc[4] * rd, acc[5] * rd, acc[6] * rd, acc[7] * rd};
    out4[(size_t)v * 32 + 2 * j]     = o0;
    out4[(size_t)v * 32 + 2 * j + 1] = o1;
}

extern "C" void kernel_launch(void* const* d_in, const int* in_sizes, int n_in,
                              void* d_out, int out_size, void* d_ws, size_t ws_size,
                              hipStream_t stream) {
    const float* X      = (const float*)d_in[0];
    const float* W      = (const float*)d_in[1];
    const float* att    = (const float*)d_in[2];
    const int*   vertex = (const int*)d_in[3];
    const int*   edges  = (const int*)d_in[4];
    float* out = (float*)d_out;

    // -------- workspace layout (~66 MB) --------
    unsigned short* X0b = (unsigned short*)d_ws;              // N*128 bf16 (25.6 MB)
    unsigned short* Xeb = X0b + (size_t)N_V * HC;             // M*128 bf16 (25.6 MB)
    unsigned* stage_e = (unsigned*)(Xeb + (size_t)N_E * HC);  // NBUCK*CAP packed (4 MB)
    unsigned* stage_v = stage_e + (size_t)NBUCK * CAP;        // NBUCK*CAP packed (4 MB)
    int*   e_off   = (int*)(stage_v + (size_t)NBUCK * CAP);   // M+1
    int*   v_off   = e_off + (N_E + 1);                       // N+1
    int*   e_idx   = v_off + (N_V + 1);                       // NNZ
    int*   v_idx   = e_idx + NNZ_C;                           // NNZ
    float* aexp    = (float*)(v_idx + NNZ_C);                 // M*8 (pre-exp'd weights)
    int*   bcur_e  = (int*)(aexp + (size_t)N_E * H_);         // NBUCK
    int*   bcur_v  = bcur_e + NBUCK;                          // NBUCK (contiguous)
    unsigned short* Wf = (unsigned short*)(bcur_v + NBUCK);   // 128*128 bf16, fragment order

    hipMemsetAsync(bcur_e, 0, sizeof(int) * 2 * NBUCK, stream);

    wt_k<<<64, 256, 0, stream>>>(W, Wf);

    // fused: bscatter (196 blocks) || GEMM (1563 blocks, no-LDS)
    fusedA_k<<<SCAT_NB + GEMM_NB, 256, 0, stream>>>(X, Wf, X0b, edges, vertex,
                                                    bcur_e, bcur_v, stage_e, stage_v);

    bsort_k<<<2 * NBUCK, 512, 0, stream>>>(stage_e, stage_v, bcur_e, bcur_v,
                                           e_off, v_off, e_idx, v_idx);

    // edge aggregation + pre-exp'd logits (4 edges per wave)
    agg_gather_k<<<N_E / 16, 256, 0, stream>>>((const uint4*)X0b, e_off, e_idx, att,
                                               (uint4*)Xeb, aexp);

    // fused softmax + output gather (4 vertices per wave)
    out_fused_k<<<N_V / 16, 256, 0, stream>>>((const uint4*)Xeb, aexp, v_off, v_idx, out);
}

// Round 15
// 142.028 us; speedup vs baseline: 1.0746x; 1.0746x over previous
//
#include <hip/hip_runtime.h>
#include <hip/hip_bf16.h>

#define N_V   100000
#define N_E   100000
#define NNZ_C 800000
#define HC    128
#define H_    8
#define C_    16
#define NEG   0.2f
#define BSH   9                      // bucket shift: 512 keys per bucket
#define KPB   512
#define NBUCK 196                    // ceil(100000/512)
#define CAP   5120                   // staging capacity per bucket (mean ~4082, >15 sigma)
#define CHUNK 4096                   // elements per bscatter block (196 blocks)
#define SCAT_NB ((NNZ_C + CHUNK - 1) / CHUNK)
#define GEMM_NB ((N_V + 63) / 64)    // 1563: 64 rows per block, 16 per wave

typedef __attribute__((ext_vector_type(8))) short bf16x8;
typedef __attribute__((ext_vector_type(4))) float f32x4;

__device__ __forceinline__ short f2bf(float f) {
    unsigned u = __float_as_uint(f);
    unsigned r = (u + 0x7FFFu + ((u >> 16) & 1u)) >> 16;   // RNE
    return (short)r;
}
__device__ __forceinline__ float bf2f(unsigned short u) {
    return __uint_as_float(((unsigned)u) << 16);
}
__device__ __forceinline__ unsigned pack2(float lo, float hi) {
    return ((unsigned)(unsigned short)f2bf(hi) << 16) | (unsigned short)f2bf(lo);
}
__device__ __forceinline__ void acc8w(float* acc, uint4 p, float wt) {
    acc[0] += __uint_as_float(p.x << 16) * wt;
    acc[1] += __uint_as_float(p.x & 0xFFFF0000u) * wt;
    acc[2] += __uint_as_float(p.y << 16) * wt;
    acc[3] += __uint_as_float(p.y & 0xFFFF0000u) * wt;
    acc[4] += __uint_as_float(p.z << 16) * wt;
    acc[5] += __uint_as_float(p.z & 0xFFFF0000u) * wt;
    acc[6] += __uint_as_float(p.w << 16) * wt;
    acc[7] += __uint_as_float(p.w & 0xFFFF0000u) * wt;
}
__device__ __forceinline__ void acc8(float* acc, uint4 p) {
    acc[0] += __uint_as_float(p.x << 16);
    acc[1] += __uint_as_float(p.x & 0xFFFF0000u);
    acc[2] += __uint_as_float(p.y << 16);
    acc[3] += __uint_as_float(p.y & 0xFFFF0000u);
    acc[4] += __uint_as_float(p.z << 16);
    acc[5] += __uint_as_float(p.z & 0xFFFF0000u);
    acc[6] += __uint_as_float(p.w << 16);
    acc[7] += __uint_as_float(p.w & 0xFFFF0000u);
}

// ---------------- per-bucket counting sort body (512 threads) ----------------
__device__ __forceinline__ void bsort_body(const unsigned* __restrict__ stage,
                                           const int* __restrict__ bcnt,
                                           int* __restrict__ off, int* __restrict__ idx,
                                           int b, int t, int* sb, int* cntk, int* loc) {
    if (t < 256) sb[t] = (t < NBUCK) ? bcnt[t] : 0;
    cntk[t] = 0;
    __syncthreads();
    for (int dd = 1; dd < 256; dd <<= 1) {
        int v = (t < 256 && t >= dd) ? sb[t - dd] : 0;
        __syncthreads();
        if (t < 256 && t >= dd) sb[t] += v;
        __syncthreads();
    }
    int cnt = bcnt[b];
    int bbase = sb[b] - cnt;                      // exclusive prefix over buckets
    const unsigned* st = stage + (size_t)b * CAP;

    for (int i = t; i < cnt; i += 512)
        atomicAdd(&cntk[st[i] >> 17], 1);
    __syncthreads();
    int val = cntk[t];
    loc[t] = val;
    __syncthreads();
    for (int dd = 1; dd < 512; dd <<= 1) {
        int tv = (t >= dd) ? loc[t - dd] : 0;
        __syncthreads();
        loc[t] += tv;
        __syncthreads();
    }
    int pos0 = bbase + loc[t] - val;
    int key = (b << BSH) + t;
    if (key < N_V) off[key] = pos0;               // N_V == N_E
    cntk[t] = pos0;                               // becomes global cursor
    __syncthreads();
    for (int i = t; i < cnt; i += 512) {
        unsigned p = st[i];
        int pos = atomicAdd(&cntk[p >> 17], 1);
        idx[pos] = (int)(p & 0x1FFFF);
    }
}

// ---------------- W -> MFMA B-fragment order + cursor init + CSR endpoints ----------------
__global__ __launch_bounds__(256) void wt_k(const float* __restrict__ W, unsigned short* __restrict__ Wf,
                                            int* __restrict__ bcur, int* __restrict__ e_off,
                                            int* __restrict__ v_off) {
    int i = blockIdx.x * 256 + threadIdx.x;    // 16384 elements
    if (i < 2 * NBUCK) bcur[i] = 0;            // bcur_e ++ bcur_v contiguous
    if (i == 0) { e_off[N_E] = NNZ_C; v_off[N_V] = NNZ_C; }
    int j    = i & 7;
    int lane = (i >> 3) & 63;
    int ct   = (i >> 9) & 7;
    int ks   = i >> 12;
    int kq = lane >> 4, cl = lane & 15;
    int k = 32 * ks + ((j < 4) ? (4 * kq + j) : (16 + 4 * kq + (j - 4)));
    int c = 16 * ct + cl;
    Wf[i] = (unsigned short)f2bf(W[k * 128 + c]);
}

// ---------------- fused A: bscatter (blocks 0..SCAT_NB-1)  ||  no-LDS MFMA GEMM ----------------
__global__ __launch_bounds__(256) void fusedA_k(const float* __restrict__ X,
                                                const unsigned short* __restrict__ Wf,
                                                unsigned short* __restrict__ X0b,
                                                const int* __restrict__ edges,
                                                const int* __restrict__ vertex,
                                                int* __restrict__ bcur_e, int* __restrict__ bcur_v,
                                                unsigned* __restrict__ stage_e, unsigned* __restrict__ stage_v) {
    __shared__ int he[NBUCK], hv[NBUCK];       // scatter half only (1.6 KB)
    int tid = threadIdx.x;

    if (blockIdx.x >= SCAT_NB) {
        int blk = blockIdx.x - SCAT_NB;
        int lane = tid & 63;
        int cl = lane & 15, kq = lane >> 4;
        int base = blk * 64 + (tid >> 6) * 16;
        int rowA = base + cl;
        int srcRow = (rowA < N_V) ? rowA : (N_V - 1);

        f32x4 acc[8] = {};
        const float4* X4 = (const float4*)X;
        const bf16x8* Wf8 = (const bf16x8*)Wf;

        #pragma unroll
        for (int ks = 0; ks < 4; ++ks) {
            float4 a0 = X4[(size_t)srcRow * 32 + 8 * ks + kq];
            float4 a1 = X4[(size_t)srcRow * 32 + 8 * ks + 4 + kq];
            bf16x8 af;
            af[0] = f2bf(a0.x); af[1] = f2bf(a0.y); af[2] = f2bf(a0.z); af[3] = f2bf(a0.w);
            af[4] = f2bf(a1.x); af[5] = f2bf(a1.y); af[6] = f2bf(a1.z); af[7] = f2bf(a1.w);
            #pragma unroll
            for (int ct = 0; ct < 8; ++ct) {
                bf16x8 bf = Wf8[((ks * 8 + ct) << 6) + lane];   // coalesced, L1-hot
                acc[ct] = __builtin_amdgcn_mfma_f32_16x16x32_bf16(af, bf, acc[ct], 0, 0, 0);
            }
        }
        int rbase = base + kq * 4;
        #pragma unroll
        for (int ct = 0; ct < 8; ++ct) {
            #pragma unroll
            for (int r = 0; r < 4; ++r) {
                int row = rbase + r;
                if (row < N_V) X0b[(size_t)row * 128 + ct * 16 + cl] = (unsigned short)f2bf(acc[ct][r]);
            }
        }
    } else {
        for (int i = tid; i < NBUCK; i += 256) { he[i] = 0; hv[i] = 0; }
        __syncthreads();
        int e0 = blockIdx.x * CHUNK;
        int e1 = e0 + CHUNK; if (e1 > NNZ_C) e1 = NNZ_C;
        for (int i = e0 + tid; i < e1; i += 256) {
            atomicAdd(&he[edges[i] >> BSH], 1);
            atomicAdd(&hv[vertex[i] >> BSH], 1);
        }
        __syncthreads();
        for (int i = tid; i < NBUCK; i += 256) {
            int c = he[i]; he[i] = c ? atomicAdd(&bcur_e[i], c) : 0;
            c = hv[i];     hv[i] = c ? atomicAdd(&bcur_v[i], c) : 0;
        }
        __syncthreads();
        for (int i = e0 + tid; i < e1; i += 256) {
            int ed = edges[i], v = vertex[i];
            int be = ed >> BSH, bv = v >> BSH;
            int pe = atomicAdd(&he[be], 1);
            stage_e[(size_t)be * CAP + pe] = ((unsigned)(ed & (KPB - 1)) << 17) | (unsigned)v;
            int pv = atomicAdd(&hv[bv], 1);
            stage_v[(size_t)bv * CAP + pv] = ((unsigned)(v & (KPB - 1)) << 17) | (unsigned)ed;
        }
    }
}

// ---------------- bsort edge side (must precede agg) ----------------
__global__ __launch_bounds__(512) void bsort_e_k(const unsigned* __restrict__ stage_e,
                                                 const int* __restrict__ bcur_e,
                                                 int* __restrict__ e_off, int* __restrict__ e_idx) {
    __shared__ int sb[256], cntk[KPB], loc[KPB];
    bsort_body(stage_e, bcur_e, e_off, e_idx, blockIdx.x, threadIdx.x, sb, cntk, loc);
}

// ---------------- merged: bsort vertex side (blocks 0..NBUCK-1) || agg_gather (rest) ----------
// agg: 512 threads = 8 waves, one wave per edge; R13 body (reg-idx + 4x-unrolled gathers).
__global__ __launch_bounds__(512) void merged_k(const unsigned* __restrict__ stage_v,
                                                const int* __restrict__ bcur_v,
                                                int* __restrict__ v_off, int* __restrict__ v_idx,
                                                const uint4* __restrict__ X0b4,
                                                const int* __restrict__ e_off,
                                                const int* __restrict__ e_idx,
                                                const float* __restrict__ att,
                                                uint4* __restrict__ Xeb4,
                                                float* __restrict__ alpha_l) {
    __shared__ int sb[256], cntk[KPB], loc[KPB];
    if (blockIdx.x < NBUCK) {
        bsort_body(stage_v, bcur_v, v_off, v_idx, blockIdx.x, threadIdx.x, sb, cntk, loc);
        return;
    }
    int wave = ((int)blockIdx.x - NBUCK) * 8 + ((int)threadIdx.x >> 6);   // edge id
    int lane = threadIdx.x & 63;
    int beg = e_off[wave], end = e_off[wave + 1];
    int deg = end - beg;
    int j = lane & 15, g = lane >> 4;

    float acc[8] = {0.f, 0.f, 0.f, 0.f, 0.f, 0.f, 0.f, 0.f};
    const uint4 Z = {0u, 0u, 0u, 0u};

    if (deg <= 64) {
        int vl = (lane < deg) ? e_idx[beg + lane] : 0;   // one coalesced idx load
        for (int r0 = 0; r0 < deg; r0 += 16) {
            int r_0 = r0 + g, r_1 = r0 + 4 + g, r_2 = r0 + 8 + g, r_3 = r0 + 12 + g;
            int v_0 = __shfl(vl, r_0), v_1 = __shfl(vl, r_1);
            int v_2 = __shfl(vl, r_2), v_3 = __shfl(vl, r_3);
            uint4 p_0 = Z, p_1 = Z, p_2 = Z, p_3 = Z;    // 4 independent loads in flight
            if (r_0 < deg) p_0 = X0b4[(size_t)v_0 * 16 + j];
            if (r_1 < deg) p_1 = X0b4[(size_t)v_1 * 16 + j];
            if (r_2 < deg) p_2 = X0b4[(size_t)v_2 * 16 + j];
            if (r_3 < deg) p_3 = X0b4[(size_t)v_3 * 16 + j];
            acc8(acc, p_0); acc8(acc, p_1); acc8(acc, p_2); acc8(acc, p_3);
        }
    } else {
        for (int i0 = beg; i0 < end; i0 += 4) {
            int i = i0 + g;
            uint4 p = Z;
            if (i < end) p = X0b4[(size_t)e_idx[i] * 16 + j];
            acc8(acc, p);
        }
    }
    #pragma unroll
    for (int k = 0; k < 8; ++k) {
        acc[k] += __shfl_xor(acc[k], 16);
        acc[k] += __shfl_xor(acc[k], 32);
    }
    float inv = 1.f / fmaxf((float)deg, 1.f);
    uint4 o;
    o.x = pack2(acc[0] * inv, acc[1] * inv);
    o.y = pack2(acc[2] * inv, acc[3] * inv);
    o.z = pack2(acc[4] * inv, acc[5] * inv);
    o.w = pack2(acc[6] * inv, acc[7] * inv);
    if (g == 0) Xeb4[(size_t)wave * 16 + j] = o;

    // logit from ROUNDED values; head = j>>1
    const float4* att4 = (const float4*)att;
    float4 A0 = att4[2 * j], A1 = att4[2 * j + 1];
    float s = bf2f((unsigned short)(o.x & 0xFFFF)) * A0.x + bf2f((unsigned short)(o.x >> 16)) * A0.y
            + bf2f((unsigned short)(o.y & 0xFFFF)) * A0.z + bf2f((unsigned short)(o.y >> 16)) * A0.w
            + bf2f((unsigned short)(o.z & 0xFFFF)) * A1.x + bf2f((unsigned short)(o.z >> 16)) * A1.y
            + bf2f((unsigned short)(o.w & 0xFFFF)) * A1.z + bf2f((unsigned short)(o.w >> 16)) * A1.w;
    s += __shfl_xor(s, 1);
    if (g == 0 && (j & 1) == 0) {
        s = (s >= 0.f) ? s : NEG * s;          // leaky applied once
        alpha_l[wave * 8 + (j >> 1)] = s;
    }
}

// ---------------- fused softmax + weighted gather: single-pass, no-max (R13 body) ----------
__global__ __launch_bounds__(256) void out_fused_k(const uint4* __restrict__ Xeb4,
                                                   const float* __restrict__ alpha_l,
                                                   const int* __restrict__ v_off,
                                                   const int* __restrict__ v_idx,
                                                   float* __restrict__ out) {
    int wave = (int)((blockIdx.x * 256 + threadIdx.x) >> 6);
    int lane = threadIdx.x & 63;
    if (wave >= N_V) return;
    int beg = v_off[wave], end = v_off[wave + 1];
    int deg = end - beg;
    int j = lane & 15, g = lane >> 4, h = j >> 1;

    float acc[8] = {0.f, 0.f, 0.f, 0.f, 0.f, 0.f, 0.f, 0.f};
    float d = 0.f;
    const uint4 Z = {0u, 0u, 0u, 0u};

    if (deg <= 64) {
        int vl = (lane < deg) ? v_idx[beg + lane] : 0;   // one coalesced idx load
        for (int r0 = 0; r0 < deg; r0 += 16) {
            int r_0 = r0 + g, r_1 = r0 + 4 + g, r_2 = r0 + 8 + g, r_3 = r0 + 12 + g;
            int e_0 = __shfl(vl, r_0), e_1 = __shfl(vl, r_1);
            int e_2 = __shfl(vl, r_2), e_3 = __shfl(vl, r_3);
            bool b_0 = r_0 < deg, b_1 = r_1 < deg, b_2 = r_2 < deg, b_3 = r_3 < deg;
            float a_0 = 0.f, a_1 = 0.f, a_2 = 0.f, a_3 = 0.f;
            uint4 p_0 = Z, p_1 = Z, p_2 = Z, p_3 = Z;    // 8 independent loads in flight
            if (b_0) { a_0 = alpha_l[e_0 * 8 + h]; p_0 = Xeb4[(size_t)e_0 * 16 + j]; }
            if (b_1) { a_1 = alpha_l[e_1 * 8 + h]; p_1 = Xeb4[(size_t)e_1 * 16 + j]; }
            if (b_2) { a_2 = alpha_l[e_2 * 8 + h]; p_2 = Xeb4[(size_t)e_2 * 16 + j]; }
            if (b_3) { a_3 = alpha_l[e_3 * 8 + h]; p_3 = Xeb4[(size_t)e_3 * 16 + j]; }
            float w_0 = b_0 ? __expf(a_0) : 0.f;
            float w_1 = b_1 ? __expf(a_1) : 0.f;
            float w_2 = b_2 ? __expf(a_2) : 0.f;
            float w_3 = b_3 ? __expf(a_3) : 0.f;
            d += w_0 + w_1 + w_2 + w_3;
            acc8w(acc, p_0, w_0); acc8w(acc, p_1, w_1);
            acc8w(acc, p_2, w_2); acc8w(acc, p_3, w_3);
        }
    } else {
        for (int i0 = beg; i0 < end; i0 += 4) {
            int i = i0 + g;
            float w = 0.f;
            uint4 p = Z;
            if (i < end) {
                int ed = v_idx[i];
                w = __expf(alpha_l[ed * 8 + h]);
                p = Xeb4[(size_t)ed * 16 + j];
            }
            d += w;
            acc8w(acc, p, w);
        }
    }
    d += __shfl_xor(d, 16);
    d += __shfl_xor(d, 32);
    float rd = 1.f / (d + 1e-16f);
    #pragma unroll
    for (int k = 0; k < 8; ++k) {
        acc[k] += __shfl_xor(acc[k], 16);
        acc[k] += __shfl_xor(acc[k], 32);
        acc[k] *= rd;
    }
    if (g == 0) {
        float4* out4 = (float4*)out;
        float4 o0 = {acc[0], acc[1], acc[2], acc[3]};
        float4 o1 = {acc[4], acc[5], acc[6], acc[7]};
        out4[(size_t)wave * 32 + 2 * j]     = o0;
        out4[(size_t)wave * 32 + 2 * j + 1] = o1;
    }
}

extern "C" void kernel_launch(void* const* d_in, const int* in_sizes, int n_in,
                              void* d_out, int out_size, void* d_ws, size_t ws_size,
                              hipStream_t stream) {
    const float* X      = (const float*)d_in[0];
    const float* W      = (const float*)d_in[1];
    const float* att    = (const float*)d_in[2];
    const int*   vertex = (const int*)d_in[3];
    const int*   edges  = (const int*)d_in[4];
    float* out = (float*)d_out;

    // -------- workspace layout (~66 MB) --------
    unsigned short* X0b = (unsigned short*)d_ws;              // N*128 bf16 (25.6 MB)
    unsigned short* Xeb = X0b + (size_t)N_V * HC;             // M*128 bf16 (25.6 MB)
    unsigned* stage_e = (unsigned*)(Xeb + (size_t)N_E * HC);  // NBUCK*CAP packed (4 MB)
    unsigned* stage_v = stage_e + (size_t)NBUCK * CAP;        // NBUCK*CAP packed (4 MB)
    int*   e_off   = (int*)(stage_v + (size_t)NBUCK * CAP);   // M+1
    int*   v_off   = e_off + (N_E + 1);                       // N+1
    int*   e_idx   = v_off + (N_V + 1);                       // NNZ
    int*   v_idx   = e_idx + NNZ_C;                           // NNZ
    float* alpha_l = (float*)(v_idx + NNZ_C);                 // M*8
    int*   bcur_e  = (int*)(alpha_l + (size_t)N_E * H_);      // NBUCK
    int*   bcur_v  = bcur_e + NBUCK;                          // NBUCK (contiguous)
    unsigned short* Wf = (unsigned short*)(bcur_v + NBUCK);   // 128*128 bf16, fragment order

    // W -> fragment order; zero bucket cursors; CSR endpoints
    wt_k<<<64, 256, 0, stream>>>(W, Wf, bcur_e, e_off, v_off);

    // fused: bscatter (196 blocks) || GEMM (1563 blocks, no-LDS)
    fusedA_k<<<SCAT_NB + GEMM_NB, 256, 0, stream>>>(X, Wf, X0b, edges, vertex,
                                                    bcur_e, bcur_v, stage_e, stage_v);

    // edge CSR (needed by agg)
    bsort_e_k<<<NBUCK, 512, 0, stream>>>(stage_e, bcur_e, e_off, e_idx);

    // vertex CSR (196 blocks) || edge aggregation + logits (12500 blocks, 8 edges each)
    merged_k<<<NBUCK + N_E / 8, 512, 0, stream>>>(stage_v, bcur_v, v_off, v_idx,
                                                  (const uint4*)X0b, e_off, e_idx, att,
                                                  (uint4*)Xeb, alpha_l);

    // fused softmax + output gather (single-pass, no-max)
    out_fused_k<<<(N_V * 64) / 256, 256, 0, stream>>>((const uint4*)Xeb, alpha_l, v_off, v_idx, out);
}